// Round 1
// baseline (56.172 us; speedup 1.0000x reference)
//
#include <hip/hip_runtime.h>

// loss = (2n*S2 - 2*S1^2) / (n*(n-1)),  S1 = sum(e), S2 = sum(e^2), e = pred - tgt
//
// n = 16384 fixed -> 128 KB total input. The harness re-poisons the 256 MiB
// workspace every iteration (rocprof: fillBufferAligned, 39.4 us, 256 MiB
// writes), thrashing L2+L3 -> our reads are HBM-latency misses. A single
// block (1 CU) serializes 128 KB through one CU's outstanding-miss capacity
// (~10+ us). Fix: 64 blocks x 64 threads across 64 CUs / all 8 XCDs, each
// lane loads one float4 from each array -> ONE latency round-trip per CU,
// 64-way miss parallelism. Cross-block combine via per-block float2 partial
// slots in d_ws (overwritten before read -> poison-safe) + a second 1-wave
// reduction kernel. Same-stream dispatch ordering gives cross-XCD coherence
// (kernel-boundary release/acquire).

#define RDL_NB 64   // blocks (CUs engaged); 64 = 8 per XCD
#define RDL_NT 64   // threads per block = 1 wave

__global__ __launch_bounds__(RDL_NT)
void RDL_partial(const float* __restrict__ pred,
                 const float* __restrict__ tgt,
                 float2* __restrict__ ws, int n) {
    const float4* __restrict__ p4 = reinterpret_cast<const float4*>(pred);
    const float4* __restrict__ t4 = reinterpret_cast<const float4*>(tgt);
    const int nvec = n >> 2;

    float s1 = 0.f, s2 = 0.f;

    // For n = 16384: nvec = 4096 = RDL_NB*RDL_NT -> exactly one iteration,
    // two independent dwordx4 loads issued before any waitcnt.
    for (int i = blockIdx.x * RDL_NT + threadIdx.x; i < nvec;
         i += gridDim.x * RDL_NT) {
        float4 p = p4[i];
        float4 t = t4[i];
        float e0 = p.x - t.x;
        float e1 = p.y - t.y;
        float e2 = p.z - t.z;
        float e3 = p.w - t.w;
        s1 += (e0 + e1) + (e2 + e3);
        s2 += (e0 * e0 + e1 * e1) + (e2 * e2 + e3 * e3);
    }

    // scalar tail for n % 4 != 0 (never taken for this problem)
    if (blockIdx.x == 0) {
        for (int i = (nvec << 2) + threadIdx.x; i < n; i += RDL_NT) {
            float e = pred[i] - tgt[i];
            s1 += e;
            s2 += e * e;
        }
    }

    // wave-level reduction across the block's single 64-lane wave
    #pragma unroll
    for (int off = 32; off > 0; off >>= 1) {
        s1 += __shfl_down(s1, off, 64);
        s2 += __shfl_down(s2, off, 64);
    }

    if (threadIdx.x == 0) ws[blockIdx.x] = make_float2(s1, s2);
}

__global__ __launch_bounds__(RDL_NT)
void RDL_final(const float2* __restrict__ ws, float* __restrict__ out,
               int n, int nb) {
    // nb = 64 partials, one per lane; accumulate in double for the final
    // closed-form (matches previous version's double epilogue, absmax 0.0)
    double s1 = 0.0, s2 = 0.0;
    for (int i = threadIdx.x; i < nb; i += RDL_NT) {
        float2 v = ws[i];
        s1 += (double)v.x;
        s2 += (double)v.y;
    }
    #pragma unroll
    for (int off = 32; off > 0; off >>= 1) {
        s1 += __shfl_down(s1, off, 64);
        s2 += __shfl_down(s2, off, 64);
    }
    if (threadIdx.x == 0) {
        const double nf = (double)n;
        const double loss = (2.0 * nf * s2 - 2.0 * s1 * s1) / (nf * (nf - 1.0));
        out[0] = (float)loss;
    }
}

extern "C" void kernel_launch(void* const* d_in, const int* in_sizes, int n_in,
                              void* d_out, int out_size, void* d_ws, size_t ws_size,
                              hipStream_t stream) {
    const float* pred = (const float*)d_in[0];
    const float* tgt  = (const float*)d_in[1];
    float* out = (float*)d_out;
    float2* ws = (float2*)d_ws;   // 64 * 8 B = 512 B used
    const int n = in_sizes[0];    // 16384

    RDL_partial<<<RDL_NB, RDL_NT, 0, stream>>>(pred, tgt, ws, n);
    RDL_final<<<1, RDL_NT, 0, stream>>>(ws, out, n, RDL_NB);
}